// Round 11
// baseline (386.122 us; speedup 1.0000x reference)
//
#include <hip/hip_runtime.h>
#include <math.h>

#define V 2
#define NN 100000
#define KK 8
#define DD 128
#define TILE_N 128
#define SL 132
#define NT 782            /* ceil(100000/128) */
#define CH 7              /* tiles per maha block */
#define CPX 14            /* chunks per XCD: 8*14 = 112 = ceil(782/7) exactly */
#define NPAD 100096       /* NT*128 */
#define LOG2PI 1.8378770664093454f
#define LOG_1EM6 -13.815510557964274f

// Packed triangular W image (per r), COLUMN-MAJOR-BY-CHUNK layout (proven
// round 10: SQ_LDS_BANK_CONFLICT = 0): 4 row-blocks of 32 rows; block R
// stores g-slots 0..4R+3. 16B chunk (R,g,rl) at byte hbase[R] + g*512 +
// rl*16, hbase = {0,2048,6144,12288}; lo copy at +20480 B. Half-wave reads
// are contiguous 512B; all ds_reads share one vaddr + offset immediates.
// Total 40960 B EXACTLY -> 4 blocks/CU = 160 KiB (bl_s removed this round).
#define IMG_PB 40960
#define IMG_LO_US 10240     /* ushort offset of lo half */

// ws layout (bytes):
//  IMG:  [16][40960]  packed bf16 triangular image (hi then lo)
//  LF:   [16][69632]  L fp32 row-major stride 132 (67584 B used)
//  B:    [16][128] float
//  C:    [16] float
//  MAHA: [16][NPAD] float
//  PEN:  [16] float   penalty partials (replaces atomicAdd+zero_kernel)
#define LF_B   1114112
#define LF_STRIDE 69632
#define BV_B   2228224
#define C_B    2236416
#define MAHA_B 2236480
#define PEN_B  8642624     /* MAHA_B + 16*NPAD*4 */

// out layout (floats): energies [N][V] | weights [N][V] | total_energies | total_penalty
#define OUT_W_OFF (NN*V)
#define OUT_TE (2*NN*V)
#define OUT_TP (2*NN*V + 1)

typedef __attribute__((ext_vector_type(8)))  short bf16x8;
typedef __attribute__((ext_vector_type(4)))  float f32x4;
typedef __attribute__((ext_vector_type(16))) float f32x16;
typedef __attribute__((ext_vector_type(4)))  unsigned u32x4;

__device__ __forceinline__ unsigned short f2bf_rtn(float f) {
    unsigned u = __builtin_bit_cast(unsigned, f);
    unsigned r = u + 0x7FFFu + ((u >> 16) & 1u);
    return (unsigned short)(r >> 16);
}
__device__ __forceinline__ float bf2f(unsigned short h) {
    unsigned u = ((unsigned)h) << 16;
    return __builtin_bit_cast(float, u);
}

// Split via v_cvt_pk_bf16_f32 (HW RTN pack, no builtin -> inline asm;
// register-only VALU asm, no scheduling hazard). lo = exact residual
// f - bf2f(hi_rtn) (exact in f32: <=15 significant bits), packed RTN.
// 6 VALU ops per 2 elements vs 8 for the perm/trunc scheme — and hi is
// now true RTN (slightly better accuracy than trunc).
__device__ __forceinline__ void cvt_pair(float f0, float f1, unsigned& hi, unsigned& lo) {
    unsigned hp;
    asm("v_cvt_pk_bf16_f32 %0, %1, %2" : "=v"(hp) : "v"(f0), "v"(f1));
    float h0 = __builtin_bit_cast(float, hp << 16);
    float h1 = __builtin_bit_cast(float, hp & 0xFFFF0000u);
    float r0 = f0 - h0;
    float r1 = f1 - h1;
    unsigned lp;
    asm("v_cvt_pk_bf16_f32 %0, %1, %2" : "=v"(lp) : "v"(r0), "v"(r1));
    hi = hp;
    lo = lp;
}

// One block of 256 threads per (v,k): panel Cholesky,
// forward solve L b = mu, write L + b + c + penalty partial + logdet.
// Also zeroes out[OUT_TE] (block 0) — runs before finalize in stream order,
// so the separate zero_kernel launch is gone.
__global__ __launch_bounds__(256) void prep_chol(const float* __restrict__ phi,
                                                 const float* __restrict__ mu,
                                                 const float* __restrict__ sigma,
                                                 void* __restrict__ wsv,
                                                 float* __restrict__ out) {
    __shared__ float Lf[DD * SL];          // L row-major, stride 132 (upper zeroed)
    __shared__ float P[8][SL];             // current panel, col-major
    __shared__ float dvec[DD];             // raw pivots d_c = L_cc^2
    __shared__ float mulds[DD];
    __shared__ float red[256];
    __shared__ float Bv[8];
    __shared__ float Bb[DD];

    const int tid = threadIdx.x;
    const int vk  = blockIdx.x;
    const int v   = vk >> 3;
    const int k   = vk & 7;
    const int R   = tid >> 4;
    const int C   = tid & 15;

    if (vk == 0 && tid == 0) out[OUT_TE] = 0.0f;
    if (tid < DD) mulds[tid] = mu[vk * DD + tid];

    float A[8][8];
    const float* sig = sigma + (size_t)vk * DD * DD;
    float pen = 0.0f;
    #pragma unroll
    for (int a = 0; a < 8; ++a) {
        const float4* p4 = (const float4*)(sig + (size_t)(8 * R + a) * DD + 8 * C);
        float4 x = p4[0], y = p4[1];
        A[a][0] = x.x; A[a][1] = x.y; A[a][2] = x.z; A[a][3] = x.w;
        A[a][4] = y.x; A[a][5] = y.y; A[a][6] = y.z; A[a][7] = y.w;
        if (R == C) A[a][a] += 1e-6f;
    }
    if (R == C) {
        #pragma unroll
        for (int a = 0; a < 8; ++a) pen += 1.0f / (A[a][a] + 1e-12f);
    }

    for (int i = tid; i < DD * SL; i += 256) Lf[i] = 0.0f;

    red[tid] = pen;
    __syncthreads();
    for (int s = 128; s > 0; s >>= 1) {
        if (tid < s) red[tid] += red[tid + s];
        __syncthreads();
    }
    if (tid == 0) ((float*)((char*)wsv + PEN_B))[vk] = red[0];
    __syncthreads();

    // ---- 16 panel phases ----
    for (int p = 0; p < 16; ++p) {
        if (C == p && R >= p) {
            #pragma unroll
            for (int b = 0; b < 8; ++b) {
                *(float4*)&P[b][8 * R]     = make_float4(A[0][b], A[1][b], A[2][b], A[3][b]);
                *(float4*)&P[b][8 * R + 4] = make_float4(A[4][b], A[5][b], A[6][b], A[7][b]);
            }
        }
        __syncthreads();

        if (tid < 64) {
            const int lane = tid;
            const int r1 = 8 * p + lane;
            const int r2 = r1 + 64;
            const bool ok2 = (r2 < DD);
            float pr1[8], pr2[8], rs[8];
            #pragma unroll
            for (int j = 0; j < 8; ++j) {
                pr1[j] = (r1 < DD) ? P[j][r1] : 0.0f;
                pr2[j] = ok2 ? P[j][r2] : 0.0f;
            }
            #pragma unroll
            for (int j = 0; j < 8; ++j) {
                if (lane >= j && lane < 8) Bv[lane] = pr1[j];
                __builtin_amdgcn_wave_barrier();
                float bv[8];
                #pragma unroll
                for (int m = 0; m < 8; ++m) bv[m] = Bv[m];
                __builtin_amdgcn_wave_barrier();
                float piv = bv[j];
                if (lane == j) dvec[8 * p + j] = piv;
                float inv2 = 1.0f / piv;
                rs[j] = rsqrtf(piv);
                float m1 = pr1[j] * inv2;
                float m2 = pr2[j] * inv2;
                #pragma unroll
                for (int j2 = 0; j2 < 8; ++j2) {
                    if (j2 > j) {
                        if (lane > j) pr1[j2] -= m1 * bv[j2];
                        pr2[j2] -= m2 * bv[j2];
                    }
                }
            }
            #pragma unroll
            for (int j = 0; j < 8; ++j) {
                if (r1 < DD) {
                    float v1 = (lane >= j) ? pr1[j] * rs[j] : 0.0f;
                    P[j][r1] = v1;
                    Lf[r1 * SL + 8 * p + j] = v1;
                }
                if (ok2) {
                    float v2 = pr2[j] * rs[j];
                    P[j][r2] = v2;
                    Lf[r2 * SL + 8 * p + j] = v2;
                }
            }
        }
        __syncthreads();

        if (C > p && R >= p) {
            #pragma unroll
            for (int j = 0; j < 8; ++j) {
                float4 a0 = *(const float4*)&P[j][8 * R];
                float4 a1 = *(const float4*)&P[j][8 * R + 4];
                float4 b0 = *(const float4*)&P[j][8 * C];
                float4 b1 = *(const float4*)&P[j][8 * C + 4];
                float ra[8] = {a0.x, a0.y, a0.z, a0.w, a1.x, a1.y, a1.z, a1.w};
                float rb[8] = {b0.x, b0.y, b0.z, b0.w, b1.x, b1.y, b1.z, b1.w};
                #pragma unroll
                for (int a = 0; a < 8; ++a)
                    #pragma unroll
                    for (int b = 0; b < 8; ++b)
                        A[a][b] -= ra[a] * rb[b];
            }
        }
        __syncthreads();
    }

    // forward solve L b = mu (wave 0, wave-synchronous)
    if (tid < 64) {
        const int lane = tid;
        float acc0 = mulds[lane];
        float acc1 = mulds[lane + 64];
        for (int j = 0; j < DD; ++j) {
            if (j < 64) { if (lane == j)      Bb[j] = acc0 / Lf[j * SL + j]; }
            else        { if (lane == j - 64) Bb[j] = acc1 / Lf[j * SL + j]; }
            __builtin_amdgcn_wave_barrier();
            float bj = Bb[j];
            __builtin_amdgcn_wave_barrier();
            if (lane > j)      acc0 -= Lf[lane * SL + j] * bj;
            if (lane + 64 > j) acc1 -= Lf[(lane + 64) * SL + j] * bj;
        }
    }
    __syncthreads();
    if (tid < DD) ((float*)((char*)wsv + BV_B))[vk * DD + tid] = Bb[tid];

    // write L to global (fp32, stride 132)
    {
        float4* Lg = (float4*)((char*)wsv + LF_B + (size_t)vk * LF_STRIDE);
        const float4* Ls4 = (const float4*)Lf;
        for (int i = tid; i < DD * SL / 4; i += 256) Lg[i] = Ls4[i];
    }

    // logdet = sum log d_c (clipped) + c_k
    red[tid] = (tid < DD) ? logf(dvec[tid]) : 0.0f;
    __syncthreads();
    for (int s = 128; s > 0; s >>= 1) {
        if (tid < s) red[tid] += red[tid + s];
        __syncthreads();
    }
    if (tid == 0) {
        float logdet_c = fmaxf(red[0], LOG_1EM6);
        const float* ph = phi + v * KK;
        float m = ph[0];
        for (int i = 1; i < KK; ++i) m = fmaxf(m, ph[i]);
        float s = 0.0f;
        for (int i = 0; i < KK; ++i) s += expf(ph[i] - m);
        float logpi = ph[k] - m - logf(s);
        ((float*)((char*)wsv + C_B))[vk] = logpi - 0.5f * logdet_c - 0.5f * (float)DD * LOG2PI;
    }
}

// 64 blocks: (vk, column-group). Each block computes 32 columns of W = L^{-1}
// (8 lanes per column) and packs them into the column-major-chunk image.
__global__ __launch_bounds__(256) void prep_trsm(void* __restrict__ wsv) {
    __shared__ float Ls[DD * SL];
    __shared__ float Wc[32][SL];

    const int tid = threadIdx.x;
    const int vk  = blockIdx.x >> 2;
    const int cg  = blockIdx.x & 3;

    const float4* Lg = (const float4*)((const char*)wsv + LF_B + (size_t)vk * LF_STRIDE);
    float4* Ls4 = (float4*)Ls;
    for (int i = tid; i < DD * SL / 4; i += 256) Ls4[i] = Lg[i];
    __syncthreads();

    const int c   = tid >> 3;          // local column 0..31
    const int par = tid & 7;
    const int j   = 4 * c + cg;        // global column

    for (int e = par; e < SL; e += 8) Wc[c][e] = 0.0f;
    if (par == 0) Wc[c][j] = 1.0f / Ls[j * SL + j];
    __builtin_amdgcn_wave_barrier();

    const int pbase = j & ~3;
    for (int i = j + 1; i < DD; ++i) {
        float s = 0.0f;
        for (int p4 = pbase + 4 * par; p4 < i; p4 += 32) {
            float4 lf = *(const float4*)&Ls[i * SL + p4];
            float4 wc = *(const float4*)&Wc[c][p4];
            s += lf.x * wc.x + lf.y * wc.y + lf.z * wc.z + lf.w * wc.w;
        }
        s += __shfl_xor(s, 1, 64);
        s += __shfl_xor(s, 2, 64);
        s += __shfl_xor(s, 4, 64);
        if (par == 0) Wc[c][i] = -s / Ls[i * SL + i];
        __builtin_amdgcn_wave_barrier();
    }

    // pack column j into the column-major-chunk image:
    // element (i,j): R=i>>5 (stored iff j>>5 <= R), g=j>>3, rl=i&31;
    // ushort idx = hbus[R] + g*256 + rl*8 + (j&7); lo at +IMG_LO_US.
    unsigned short* Gh = (unsigned short*)((char*)wsv + (size_t)vk * IMG_PB);
    for (int i2 = par; i2 < DD; i2 += 8) {
        const int b = i2 >> 5;
        if ((j >> 5) > b) continue;            // col outside this block's range
        const int rl   = i2 & 31;
        const int hbus = (b == 0 ? 0 : b == 1 ? 1024 : b == 2 ? 3072 : 6144);
        const int us   = hbus + (j >> 3) * 256 + rl * 8 + (j & 7);
        float f = (i2 >= j) ? Wc[c][i2] : 0.0f;
        unsigned short hsh = f2bf_rtn(f);
        unsigned short lsh = f2bf_rtn(f - bf2f(hsh));
        Gh[us] = hsh;
        Gh[us + IMG_LO_US] = lsh;
    }
}

// 1-D grid of 1792 blocks, XCD-aware decode (proven: FETCH 402->57MB,
// CH=7 perfect XCD balance). 32x32x16 MFMA + conflict-free column-major
// LDS (round 10: conflicts = 0). THIS ROUND: bl_s dropped from LDS (b via
// per-R float4 broadcast global loads, L1/L2-hot, issued before each R's
// MFMA chain) -> LDS = 40960 B exactly = 4 blocks/CU = 16 waves/CU (+33%
// TLP); conversion via v_cvt_pk_bf16_f32 (6 VALU / 2 elems, was 8).
__global__ __launch_bounds__(256) void maha_kernel(const float* __restrict__ z,
                                                   void* __restrict__ wsv) {
    __shared__ unsigned short wl[IMG_PB / 2];

    const int tid  = threadIdx.x;
    const int lane = tid & 63;
    const int wave = tid >> 6;
    const int rl   = lane & 31;         // W-row-local == n-local
    const int h    = lane >> 5;         // k-half selector

    const int bi    = blockIdx.x;       // 0..1791
    const int xcd   = bi & 7;
    const int jj    = bi >> 3;          // 0..223
    const int r     = jj & 15;          // fast: 16 r's of a chunk adjacent on XCD
    const int lc    = jj >> 4;          // 0..13
    const int chunk = xcd * CPX + lc;   // 0..111
    const int vv    = r >> 3;

    if (chunk * CH >= NT) return;

    // stage packed W_r (10 x 4KB chunks, exact: IMG_PB = 10*4096) — linear copy
    {
        const char* src = (const char*)wsv + (size_t)r * IMG_PB;
        char* dst = (char*)wl;
        const int lane_off = wave * 1024 + lane * 16;
        #pragma unroll
        for (int t = 0; t < 10; ++t)
            __builtin_amdgcn_global_load_lds(
                (const __attribute__((address_space(1))) void*)(src + t * 4096 + lane_off),
                (__attribute__((address_space(3))) void*)(dst + t * 4096 + wave * 1024),
                16, 0, 0);
    }
    __syncthreads();   // single drain; nothing in-flight afterwards

    const float* zbase = z + (size_t)vv * NN * DD;
    const float* bvg = (const float*)((const char*)wsv + BV_B) + r * DD + 4 * h;
    float* mrow = (float*)((char*)wsv + MAHA_B) + (size_t)r * NPAD;
    const char* wlb = (const char*)wl + (h * 512 + rl * 16);   // single vaddr base

    for (int ti = 0; ti < CH; ++ti) {
        const int t = chunk * CH + ti;
        if (t >= NT) break;
        const int n0 = t * TILE_N;

        // load this lane's z fragments: n = n0+wave*32+rl, k = s*16 + h*8 + 0..7
        const int n   = n0 + wave * 32 + rl;
        const bool ok = (n < NN);
        const float* zp = zbase + (size_t)n * DD + h * 8;

        float4 raw[8][2];
        #pragma unroll
        for (int s = 0; s < 8; ++s) {
            if (ok) {
                raw[s][0] = *(const float4*)(zp + s * 16);
                raw[s][1] = *(const float4*)(zp + s * 16 + 4);
            } else {
                raw[s][0] = make_float4(0.f, 0.f, 0.f, 0.f);
                raw[s][1] = make_float4(0.f, 0.f, 0.f, 0.f);
            }
        }

        u32x4 zh8[8], zl8[8];
        #pragma unroll
        for (int s = 0; s < 8; ++s) {
            float4 a = raw[s][0];
            float4 b = raw[s][1];
            unsigned h0, l0, h1, l1, h2, l2, h3, l3;
            cvt_pair(a.x, a.y, h0, l0);
            cvt_pair(a.z, a.w, h1, l1);
            cvt_pair(b.x, b.y, h2, l2);
            cvt_pair(b.z, b.w, h3, l3);
            u32x4 th, tl;
            th[0] = h0; th[1] = h1; th[2] = h2; th[3] = h3;
            tl[0] = l0; tl[1] = l1; tl[2] = l2; tl[3] = l3;
            zh8[s] = th;
            zl8[s] = tl;
        }

        // row-block loop: per R one 32x32 D tile (16 regs), triangular K
        // (s <= 2R+1). b loads issued BEFORE the MFMA chain: latency hides
        // under it; broadcast (same addr per half-wave), L1-hot (8 KB total).
        float pa = 0.0f;
        #pragma unroll
        for (int R = 0; R < 4; ++R) {
            const int hb = (R == 0 ? 0 : R == 1 ? 2048 : R == 2 ? 6144 : 12288);
            float4 bq0 = *(const float4*)(bvg + 32 * R);
            float4 bq1 = *(const float4*)(bvg + 32 * R + 8);
            float4 bq2 = *(const float4*)(bvg + 32 * R + 16);
            float4 bq3 = *(const float4*)(bvg + 32 * R + 24);
            f32x16 D = (f32x16)(0.0f);
            #pragma unroll
            for (int s = 0; s <= 2 * R + 1; ++s) {
                const int off = hb + 1024 * s;       // + vaddr's h*512 gives g=2s+h
                bf16x8 wh  = *(const bf16x8*)(wlb + off);
                bf16x8 wlo = *(const bf16x8*)(wlb + off + 2 * IMG_LO_US);
                bf16x8 zh = __builtin_bit_cast(bf16x8, zh8[s]);
                bf16x8 zl = __builtin_bit_cast(bf16x8, zl8[s]);
                D = __builtin_amdgcn_mfma_f32_32x32x16_bf16(wh,  zh, D, 0, 0, 0);
                D = __builtin_amdgcn_mfma_f32_32x32x16_bf16(wlo, zh, D, 0, 0, 0);
                D = __builtin_amdgcn_mfma_f32_32x32x16_bf16(wh,  zl, D, 0, 0, 0);
            }
            // rows for regs 4q..4q+3: 32R + 8q + 4h + {0,1,2,3} (consecutive)
            {
                float t0, t1, t2, t3;
                t0 = D[0]  - bq0.x; t1 = D[1]  - bq0.y; t2 = D[2]  - bq0.z; t3 = D[3]  - bq0.w;
                pa += t0 * t0 + t1 * t1 + t2 * t2 + t3 * t3;
                t0 = D[4]  - bq1.x; t1 = D[5]  - bq1.y; t2 = D[6]  - bq1.z; t3 = D[7]  - bq1.w;
                pa += t0 * t0 + t1 * t1 + t2 * t2 + t3 * t3;
                t0 = D[8]  - bq2.x; t1 = D[9]  - bq2.y; t2 = D[10] - bq2.z; t3 = D[11] - bq2.w;
                pa += t0 * t0 + t1 * t1 + t2 * t2 + t3 * t3;
                t0 = D[12] - bq3.x; t1 = D[13] - bq3.y; t2 = D[14] - bq3.z; t3 = D[15] - bq3.w;
                pa += t0 * t0 + t1 * t1 + t2 * t2 + t3 * t3;
            }
        }

        // lane l holds half the rows for n; partner l^32 holds the other half
        pa += __shfl_xor(pa, 32, 64);
        if (lane < 32) mrow[n0 + wave * 32 + rl] = pa;
    }
}

// LSE + weights + totals from maha[16][NPAD]; block 0 also sums the 16
// penalty partials (written by prep_chol) into out[OUT_TP].
__global__ __launch_bounds__(256) void finalize_kernel(const void* __restrict__ wsv,
                                                       float* __restrict__ out) {
    __shared__ float red[256];
    __shared__ float clds[16];

    const int tid = threadIdx.x;
    if (tid < 16) clds[tid] = ((const float*)((const char*)wsv + C_B))[tid];
    __syncthreads();

    if (blockIdx.x == 0 && tid == 0) {
        const float* pp = (const float*)((const char*)wsv + PEN_B);
        float s = 0.0f;
        #pragma unroll
        for (int i = 0; i < 16; ++i) s += pp[i];
        out[OUT_TP] = s;
    }

    const float* mahap = (const float*)((const char*)wsv + MAHA_B);
    const int n = blockIdx.x * 256 + tid;
    float esum = 0.0f;

    if (n < NN) {
        float ev[V];
        #pragma unroll
        for (int vv = 0; vv < V; ++vv) {
            float lp[KK];
            float m = -1e30f;
            #pragma unroll
            for (int k = 0; k < KK; ++k) {
                int r = vv * KK + k;
                lp[k] = -0.5f * mahap[(size_t)r * NPAD + n] + clds[r];
                m = fmaxf(m, lp[k]);
            }
            float s = 0.0f;
            #pragma unroll
            for (int k = 0; k < KK; ++k) s += expf(lp[k] - m);
            ev[vv] = -(m + logf(s));
        }
        float e0 = ev[0], e1 = ev[1];
        float m = fmaxf(-e0, -e1);
        float x0 = expf(-e0 - m);
        float x1 = expf(-e1 - m);
        float inv = 1.0f / (x0 + x1);
        out[(size_t)n * V + 0] = e0;
        out[(size_t)n * V + 1] = e1;
        out[OUT_W_OFF + (size_t)n * V + 0] = x0 * inv;
        out[OUT_W_OFF + (size_t)n * V + 1] = x1 * inv;
        esum = e0 + e1;
    }

    red[tid] = esum;
    __syncthreads();
    for (int s = 128; s > 0; s >>= 1) {
        if (tid < s) red[tid] += red[tid + s];
        __syncthreads();
    }
    if (tid == 0) atomicAdd(&out[OUT_TE], red[0]);
}

extern "C" void kernel_launch(void* const* d_in, const int* in_sizes, int n_in,
                              void* d_out, int out_size, void* d_ws, size_t ws_size,
                              hipStream_t stream) {
    const float* z     = (const float*)d_in[0];
    const float* phi   = (const float*)d_in[1];
    const float* mu    = (const float*)d_in[2];
    const float* sigma = (const float*)d_in[3];
    float* out = (float*)d_out;

    hipLaunchKernelGGL(prep_chol, dim3(V * KK), dim3(256), 0, stream, phi, mu, sigma, d_ws, out);
    hipLaunchKernelGGL(prep_trsm, dim3(64), dim3(256), 0, stream, d_ws);
    hipLaunchKernelGGL(maha_kernel, dim3(8 * CPX * 16), dim3(256), 0, stream, z, d_ws);
    hipLaunchKernelGGL(finalize_kernel, dim3((NPAD + 255) / 256), dim3(256), 0, stream, d_ws, out);
}

// Round 12
// 368.742 us; speedup vs baseline: 1.0471x; 1.0471x over previous
//
#include <hip/hip_runtime.h>
#include <math.h>

#define V 2
#define NN 100000
#define KK 8
#define DD 128
#define TILE_N 128
#define SL 132
#define NT 782            /* ceil(100000/128) */
#define CH 7              /* tiles per maha block */
#define CPX 14            /* chunks per XCD: 8*14 = 112 = ceil(782/7) exactly */
#define NPAD 100096       /* NT*128 */
#define LOG2PI 1.8378770664093454f
#define LOG_1EM6 -13.815510557964274f

// Packed triangular W image (per r), COLUMN-MAJOR-BY-CHUNK layout (proven
// round 10: SQ_LDS_BANK_CONFLICT = 0): 4 row-blocks of 32 rows; block R
// stores g-slots 0..4R+3. 16B chunk (R,g,rl) at byte hbase[R] + g*512 +
// rl*16, hbase = {0,2048,6144,12288}; lo copy at +20480 B. Half-wave reads
// are contiguous 512B; all ds_reads share one vaddr + offset immediates.
// Total 40960 B. + bl_s (512B LDS broadcast b) -> 41472 B, 3 blocks/CU.
// Round-11 lesson: b MUST be an LDS broadcast — per-R global loads stall
// every epilogue on vmcnt (149us vs 125us); 64-reg hoist breaks the budget.
#define IMG_PB 40960
#define IMG_LO_US 10240     /* ushort offset of lo half */

// ws layout (bytes):
//  IMG:  [16][40960]  packed bf16 triangular image (hi then lo)
//  LF:   [16][69632]  L fp32 row-major stride 132 (67584 B used)
//  B:    [16][128] float
//  C:    [16] float
//  MAHA: [16][NPAD] float
//  PEN:  [16] float   penalty partials (replaces atomicAdd+zero_kernel)
#define LF_B   1114112
#define LF_STRIDE 69632
#define BV_B   2228224
#define C_B    2236416
#define MAHA_B 2236480
#define PEN_B  8642624     /* MAHA_B + 16*NPAD*4 */

// out layout (floats): energies [N][V] | weights [N][V] | total_energies | total_penalty
#define OUT_W_OFF (NN*V)
#define OUT_TE (2*NN*V)
#define OUT_TP (2*NN*V + 1)

typedef __attribute__((ext_vector_type(8)))  short bf16x8;
typedef __attribute__((ext_vector_type(4)))  float f32x4;
typedef __attribute__((ext_vector_type(16))) float f32x16;
typedef __attribute__((ext_vector_type(4)))  unsigned u32x4;

__device__ __forceinline__ unsigned short f2bf_rtn(float f) {
    unsigned u = __builtin_bit_cast(unsigned, f);
    unsigned r = u + 0x7FFFu + ((u >> 16) & 1u);
    return (unsigned short)(r >> 16);
}
__device__ __forceinline__ float bf2f(unsigned short h) {
    unsigned u = ((unsigned)h) << 16;
    return __builtin_bit_cast(float, u);
}

// Split via v_cvt_pk_bf16_f32 (HW RTN pack; register-only VALU asm).
// lo = exact residual f - bf2f(hi_rtn), packed RTN. 6 VALU / 2 elems
// (proven round 11: VALUBusy 44.5 -> 31.9, absmax identical).
__device__ __forceinline__ void cvt_pair(float f0, float f1, unsigned& hi, unsigned& lo) {
    unsigned hp;
    asm("v_cvt_pk_bf16_f32 %0, %1, %2" : "=v"(hp) : "v"(f0), "v"(f1));
    float h0 = __builtin_bit_cast(float, hp << 16);
    float h1 = __builtin_bit_cast(float, hp & 0xFFFF0000u);
    float r0 = f0 - h0;
    float r1 = f1 - h1;
    unsigned lp;
    asm("v_cvt_pk_bf16_f32 %0, %1, %2" : "=v"(lp) : "v"(r0), "v"(r1));
    hi = hp;
    lo = lp;
}

// One block of 256 threads per (v,k): panel Cholesky,
// forward solve L b = mu, write L + b + c + penalty partial + logdet.
// Also zeroes out[OUT_TE] (block 0) — runs before finalize in stream order.
__global__ __launch_bounds__(256) void prep_chol(const float* __restrict__ phi,
                                                 const float* __restrict__ mu,
                                                 const float* __restrict__ sigma,
                                                 void* __restrict__ wsv,
                                                 float* __restrict__ out) {
    __shared__ float Lf[DD * SL];          // L row-major, stride 132 (upper zeroed)
    __shared__ float P[8][SL];             // current panel, col-major
    __shared__ float dvec[DD];             // raw pivots d_c = L_cc^2
    __shared__ float mulds[DD];
    __shared__ float red[256];
    __shared__ float Bv[8];
    __shared__ float Bb[DD];

    const int tid = threadIdx.x;
    const int vk  = blockIdx.x;
    const int v   = vk >> 3;
    const int k   = vk & 7;
    const int R   = tid >> 4;
    const int C   = tid & 15;

    if (vk == 0 && tid == 0) out[OUT_TE] = 0.0f;
    if (tid < DD) mulds[tid] = mu[vk * DD + tid];

    float A[8][8];
    const float* sig = sigma + (size_t)vk * DD * DD;
    float pen = 0.0f;
    #pragma unroll
    for (int a = 0; a < 8; ++a) {
        const float4* p4 = (const float4*)(sig + (size_t)(8 * R + a) * DD + 8 * C);
        float4 x = p4[0], y = p4[1];
        A[a][0] = x.x; A[a][1] = x.y; A[a][2] = x.z; A[a][3] = x.w;
        A[a][4] = y.x; A[a][5] = y.y; A[a][6] = y.z; A[a][7] = y.w;
        if (R == C) A[a][a] += 1e-6f;
    }
    if (R == C) {
        #pragma unroll
        for (int a = 0; a < 8; ++a) pen += 1.0f / (A[a][a] + 1e-12f);
    }

    for (int i = tid; i < DD * SL; i += 256) Lf[i] = 0.0f;

    red[tid] = pen;
    __syncthreads();
    for (int s = 128; s > 0; s >>= 1) {
        if (tid < s) red[tid] += red[tid + s];
        __syncthreads();
    }
    if (tid == 0) ((float*)((char*)wsv + PEN_B))[vk] = red[0];
    __syncthreads();

    // ---- 16 panel phases ----
    for (int p = 0; p < 16; ++p) {
        if (C == p && R >= p) {
            #pragma unroll
            for (int b = 0; b < 8; ++b) {
                *(float4*)&P[b][8 * R]     = make_float4(A[0][b], A[1][b], A[2][b], A[3][b]);
                *(float4*)&P[b][8 * R + 4] = make_float4(A[4][b], A[5][b], A[6][b], A[7][b]);
            }
        }
        __syncthreads();

        if (tid < 64) {
            const int lane = tid;
            const int r1 = 8 * p + lane;
            const int r2 = r1 + 64;
            const bool ok2 = (r2 < DD);
            float pr1[8], pr2[8], rs[8];
            #pragma unroll
            for (int j = 0; j < 8; ++j) {
                pr1[j] = (r1 < DD) ? P[j][r1] : 0.0f;
                pr2[j] = ok2 ? P[j][r2] : 0.0f;
            }
            #pragma unroll
            for (int j = 0; j < 8; ++j) {
                if (lane >= j && lane < 8) Bv[lane] = pr1[j];
                __builtin_amdgcn_wave_barrier();
                float bv[8];
                #pragma unroll
                for (int m = 0; m < 8; ++m) bv[m] = Bv[m];
                __builtin_amdgcn_wave_barrier();
                float piv = bv[j];
                if (lane == j) dvec[8 * p + j] = piv;
                float inv2 = 1.0f / piv;
                rs[j] = rsqrtf(piv);
                float m1 = pr1[j] * inv2;
                float m2 = pr2[j] * inv2;
                #pragma unroll
                for (int j2 = 0; j2 < 8; ++j2) {
                    if (j2 > j) {
                        if (lane > j) pr1[j2] -= m1 * bv[j2];
                        pr2[j2] -= m2 * bv[j2];
                    }
                }
            }
            #pragma unroll
            for (int j = 0; j < 8; ++j) {
                if (r1 < DD) {
                    float v1 = (lane >= j) ? pr1[j] * rs[j] : 0.0f;
                    P[j][r1] = v1;
                    Lf[r1 * SL + 8 * p + j] = v1;
                }
                if (ok2) {
                    float v2 = pr2[j] * rs[j];
                    P[j][r2] = v2;
                    Lf[r2 * SL + 8 * p + j] = v2;
                }
            }
        }
        __syncthreads();

        if (C > p && R >= p) {
            #pragma unroll
            for (int j = 0; j < 8; ++j) {
                float4 a0 = *(const float4*)&P[j][8 * R];
                float4 a1 = *(const float4*)&P[j][8 * R + 4];
                float4 b0 = *(const float4*)&P[j][8 * C];
                float4 b1 = *(const float4*)&P[j][8 * C + 4];
                float ra[8] = {a0.x, a0.y, a0.z, a0.w, a1.x, a1.y, a1.z, a1.w};
                float rb[8] = {b0.x, b0.y, b0.z, b0.w, b1.x, b1.y, b1.z, b1.w};
                #pragma unroll
                for (int a = 0; a < 8; ++a)
                    #pragma unroll
                    for (int b = 0; b < 8; ++b)
                        A[a][b] -= ra[a] * rb[b];
            }
        }
        __syncthreads();
    }

    // forward solve L b = mu (wave 0, wave-synchronous)
    if (tid < 64) {
        const int lane = tid;
        float acc0 = mulds[lane];
        float acc1 = mulds[lane + 64];
        for (int j = 0; j < DD; ++j) {
            if (j < 64) { if (lane == j)      Bb[j] = acc0 / Lf[j * SL + j]; }
            else        { if (lane == j - 64) Bb[j] = acc1 / Lf[j * SL + j]; }
            __builtin_amdgcn_wave_barrier();
            float bj = Bb[j];
            __builtin_amdgcn_wave_barrier();
            if (lane > j)      acc0 -= Lf[lane * SL + j] * bj;
            if (lane + 64 > j) acc1 -= Lf[(lane + 64) * SL + j] * bj;
        }
    }
    __syncthreads();
    if (tid < DD) ((float*)((char*)wsv + BV_B))[vk * DD + tid] = Bb[tid];

    // write L to global (fp32, stride 132)
    {
        float4* Lg = (float4*)((char*)wsv + LF_B + (size_t)vk * LF_STRIDE);
        const float4* Ls4 = (const float4*)Lf;
        for (int i = tid; i < DD * SL / 4; i += 256) Lg[i] = Ls4[i];
    }

    // logdet = sum log d_c (clipped) + c_k
    red[tid] = (tid < DD) ? logf(dvec[tid]) : 0.0f;
    __syncthreads();
    for (int s = 128; s > 0; s >>= 1) {
        if (tid < s) red[tid] += red[tid + s];
        __syncthreads();
    }
    if (tid == 0) {
        float logdet_c = fmaxf(red[0], LOG_1EM6);
        const float* ph = phi + v * KK;
        float m = ph[0];
        for (int i = 1; i < KK; ++i) m = fmaxf(m, ph[i]);
        float s = 0.0f;
        for (int i = 0; i < KK; ++i) s += expf(ph[i] - m);
        float logpi = ph[k] - m - logf(s);
        ((float*)((char*)wsv + C_B))[vk] = logpi - 0.5f * logdet_c - 0.5f * (float)DD * LOG2PI;
    }
}

// 64 blocks: (vk, column-group). Each block computes 32 columns of W = L^{-1}
// (8 lanes per column) and packs them into the column-major-chunk image.
__global__ __launch_bounds__(256) void prep_trsm(void* __restrict__ wsv) {
    __shared__ float Ls[DD * SL];
    __shared__ float Wc[32][SL];

    const int tid = threadIdx.x;
    const int vk  = blockIdx.x >> 2;
    const int cg  = blockIdx.x & 3;

    const float4* Lg = (const float4*)((const char*)wsv + LF_B + (size_t)vk * LF_STRIDE);
    float4* Ls4 = (float4*)Ls;
    for (int i = tid; i < DD * SL / 4; i += 256) Ls4[i] = Lg[i];
    __syncthreads();

    const int c   = tid >> 3;          // local column 0..31
    const int par = tid & 7;
    const int j   = 4 * c + cg;        // global column

    for (int e = par; e < SL; e += 8) Wc[c][e] = 0.0f;
    if (par == 0) Wc[c][j] = 1.0f / Ls[j * SL + j];
    __builtin_amdgcn_wave_barrier();

    const int pbase = j & ~3;
    for (int i = j + 1; i < DD; ++i) {
        float s = 0.0f;
        for (int p4 = pbase + 4 * par; p4 < i; p4 += 32) {
            float4 lf = *(const float4*)&Ls[i * SL + p4];
            float4 wc = *(const float4*)&Wc[c][p4];
            s += lf.x * wc.x + lf.y * wc.y + lf.z * wc.z + lf.w * wc.w;
        }
        s += __shfl_xor(s, 1, 64);
        s += __shfl_xor(s, 2, 64);
        s += __shfl_xor(s, 4, 64);
        if (par == 0) Wc[c][i] = -s / Ls[i * SL + i];
        __builtin_amdgcn_wave_barrier();
    }

    // pack column j into the column-major-chunk image:
    // element (i,j): R=i>>5 (stored iff j>>5 <= R), g=j>>3, rl=i&31;
    // ushort idx = hbus[R] + g*256 + rl*8 + (j&7); lo at +IMG_LO_US.
    unsigned short* Gh = (unsigned short*)((char*)wsv + (size_t)vk * IMG_PB);
    for (int i2 = par; i2 < DD; i2 += 8) {
        const int b = i2 >> 5;
        if ((j >> 5) > b) continue;            // col outside this block's range
        const int rl   = i2 & 31;
        const int hbus = (b == 0 ? 0 : b == 1 ? 1024 : b == 2 ? 3072 : 6144);
        const int us   = hbus + (j >> 3) * 256 + rl * 8 + (j & 7);
        float f = (i2 >= j) ? Wc[c][i2] : 0.0f;
        unsigned short hsh = f2bf_rtn(f);
        unsigned short lsh = f2bf_rtn(f - bf2f(hsh));
        Gh[us] = hsh;
        Gh[us + IMG_LO_US] = lsh;
    }
}

// 1-D grid of 1792 blocks, XCD-aware decode (proven: FETCH ~55MB, CH=7
// perfect XCD balance). 32x32x16 MFMA + conflict-free column-major LDS
// (conflicts = 0). b restored to LDS broadcast (bl_s, 41472 B, 3 blocks/CU
// — round-10 proven; round-11's global-b stalled every epilogue). Keeps
// round-11's cvt_pk conversion (6 VALU / 2 elems).
__global__ __launch_bounds__(256) void maha_kernel(const float* __restrict__ z,
                                                   void* __restrict__ wsv) {
    __shared__ unsigned short wl[IMG_PB / 2];
    __shared__ float bl_s[DD];

    const int tid  = threadIdx.x;
    const int lane = tid & 63;
    const int wave = tid >> 6;
    const int rl   = lane & 31;         // W-row-local == n-local
    const int h    = lane >> 5;         // k-half selector

    const int bi    = blockIdx.x;       // 0..1791
    const int xcd   = bi & 7;
    const int jj    = bi >> 3;          // 0..223
    const int r     = jj & 15;          // fast: 16 r's of a chunk adjacent on XCD
    const int lc    = jj >> 4;          // 0..13
    const int chunk = xcd * CPX + lc;   // 0..111
    const int vv    = r >> 3;

    if (chunk * CH >= NT) return;

    // stage packed W_r (10 x 4KB chunks, exact: IMG_PB = 10*4096) — linear copy
    {
        const char* src = (const char*)wsv + (size_t)r * IMG_PB;
        char* dst = (char*)wl;
        const int lane_off = wave * 1024 + lane * 16;
        #pragma unroll
        for (int t = 0; t < 10; ++t)
            __builtin_amdgcn_global_load_lds(
                (const __attribute__((address_space(1))) void*)(src + t * 4096 + lane_off),
                (__attribute__((address_space(3))) void*)(dst + t * 4096 + wave * 1024),
                16, 0, 0);
    }
    if (tid < DD) bl_s[tid] = ((const float*)((const char*)wsv + BV_B))[r * DD + tid];
    __syncthreads();   // single drain; nothing in-flight afterwards

    const float* zbase = z + (size_t)vv * NN * DD;
    float* mrow = (float*)((char*)wsv + MAHA_B) + (size_t)r * NPAD;
    const char* wlb = (const char*)wl + (h * 512 + rl * 16);   // single vaddr base

    for (int ti = 0; ti < CH; ++ti) {
        const int t = chunk * CH + ti;
        if (t >= NT) break;
        const int n0 = t * TILE_N;

        // load this lane's z fragments: n = n0+wave*32+rl, k = s*16 + h*8 + 0..7
        const int n   = n0 + wave * 32 + rl;
        const bool ok = (n < NN);
        const float* zp = zbase + (size_t)n * DD + h * 8;

        float4 raw[8][2];
        #pragma unroll
        for (int s = 0; s < 8; ++s) {
            if (ok) {
                raw[s][0] = *(const float4*)(zp + s * 16);
                raw[s][1] = *(const float4*)(zp + s * 16 + 4);
            } else {
                raw[s][0] = make_float4(0.f, 0.f, 0.f, 0.f);
                raw[s][1] = make_float4(0.f, 0.f, 0.f, 0.f);
            }
        }

        u32x4 zh8[8], zl8[8];
        #pragma unroll
        for (int s = 0; s < 8; ++s) {
            float4 a = raw[s][0];
            float4 b = raw[s][1];
            unsigned h0, l0, h1, l1, h2, l2, h3, l3;
            cvt_pair(a.x, a.y, h0, l0);
            cvt_pair(a.z, a.w, h1, l1);
            cvt_pair(b.x, b.y, h2, l2);
            cvt_pair(b.z, b.w, h3, l3);
            u32x4 th, tl;
            th[0] = h0; th[1] = h1; th[2] = h2; th[3] = h3;
            tl[0] = l0; tl[1] = l1; tl[2] = l2; tl[3] = l3;
            zh8[s] = th;
            zl8[s] = tl;
        }

        // row-block loop: per R one 32x32 D tile (16 regs), triangular K
        // (s <= 2R+1). b via LDS broadcast float4 reads (free: same addr
        // per half-wave, lgkmcnt path — no vmcnt stall).
        float pa = 0.0f;
        #pragma unroll
        for (int R = 0; R < 4; ++R) {
            const int hb = (R == 0 ? 0 : R == 1 ? 2048 : R == 2 ? 6144 : 12288);
            f32x16 D = (f32x16)(0.0f);
            #pragma unroll
            for (int s = 0; s <= 2 * R + 1; ++s) {
                const int off = hb + 1024 * s;       // + vaddr's h*512 gives g=2s+h
                bf16x8 wh  = *(const bf16x8*)(wlb + off);
                bf16x8 wlo = *(const bf16x8*)(wlb + off + 2 * IMG_LO_US);
                bf16x8 zh = __builtin_bit_cast(bf16x8, zh8[s]);
                bf16x8 zl = __builtin_bit_cast(bf16x8, zl8[s]);
                D = __builtin_amdgcn_mfma_f32_32x32x16_bf16(wh,  zh, D, 0, 0, 0);
                D = __builtin_amdgcn_mfma_f32_32x32x16_bf16(wlo, zh, D, 0, 0, 0);
                D = __builtin_amdgcn_mfma_f32_32x32x16_bf16(wh,  zl, D, 0, 0, 0);
            }
            // rows for regs 4q..4q+3: 32R + 8q + 4h + {0,1,2,3} (consecutive)
            #pragma unroll
            for (int q = 0; q < 4; ++q) {
                float4 bq = *(const float4*)&bl_s[32 * R + 8 * q + 4 * h];
                float t0 = D[4 * q + 0] - bq.x;
                float t1 = D[4 * q + 1] - bq.y;
                float t2 = D[4 * q + 2] - bq.z;
                float t3 = D[4 * q + 3] - bq.w;
                pa += t0 * t0 + t1 * t1 + t2 * t2 + t3 * t3;
            }
        }

        // lane l holds half the rows for n; partner l^32 holds the other half
        pa += __shfl_xor(pa, 32, 64);
        if (lane < 32) mrow[n0 + wave * 32 + rl] = pa;
    }
}

// LSE + weights + totals from maha[16][NPAD]; block 0 also sums the 16
// penalty partials (written by prep_chol) into out[OUT_TP].
__global__ __launch_bounds__(256) void finalize_kernel(const void* __restrict__ wsv,
                                                       float* __restrict__ out) {
    __shared__ float red[256];
    __shared__ float clds[16];

    const int tid = threadIdx.x;
    if (tid < 16) clds[tid] = ((const float*)((const char*)wsv + C_B))[tid];
    __syncthreads();

    if (blockIdx.x == 0 && tid == 0) {
        const float* pp = (const float*)((const char*)wsv + PEN_B);
        float s = 0.0f;
        #pragma unroll
        for (int i = 0; i < 16; ++i) s += pp[i];
        out[OUT_TP] = s;
    }

    const float* mahap = (const float*)((const char*)wsv + MAHA_B);
    const int n = blockIdx.x * 256 + tid;
    float esum = 0.0f;

    if (n < NN) {
        float ev[V];
        #pragma unroll
        for (int vv = 0; vv < V; ++vv) {
            float lp[KK];
            float m = -1e30f;
            #pragma unroll
            for (int k = 0; k < KK; ++k) {
                int r = vv * KK + k;
                lp[k] = -0.5f * mahap[(size_t)r * NPAD + n] + clds[r];
                m = fmaxf(m, lp[k]);
            }
            float s = 0.0f;
            #pragma unroll
            for (int k = 0; k < KK; ++k) s += expf(lp[k] - m);
            ev[vv] = -(m + logf(s));
        }
        float e0 = ev[0], e1 = ev[1];
        float m = fmaxf(-e0, -e1);
        float x0 = expf(-e0 - m);
        float x1 = expf(-e1 - m);
        float inv = 1.0f / (x0 + x1);
        out[(size_t)n * V + 0] = e0;
        out[(size_t)n * V + 1] = e1;
        out[OUT_W_OFF + (size_t)n * V + 0] = x0 * inv;
        out[OUT_W_OFF + (size_t)n * V + 1] = x1 * inv;
        esum = e0 + e1;
    }

    red[tid] = esum;
    __syncthreads();
    for (int s = 128; s > 0; s >>= 1) {
        if (tid < s) red[tid] += red[tid + s];
        __syncthreads();
    }
    if (tid == 0) atomicAdd(&out[OUT_TE], red[0]);
}

extern "C" void kernel_launch(void* const* d_in, const int* in_sizes, int n_in,
                              void* d_out, int out_size, void* d_ws, size_t ws_size,
                              hipStream_t stream) {
    const float* z     = (const float*)d_in[0];
    const float* phi   = (const float*)d_in[1];
    const float* mu    = (const float*)d_in[2];
    const float* sigma = (const float*)d_in[3];
    float* out = (float*)d_out;

    hipLaunchKernelGGL(prep_chol, dim3(V * KK), dim3(256), 0, stream, phi, mu, sigma, d_ws, out);
    hipLaunchKernelGGL(prep_trsm, dim3(64), dim3(256), 0, stream, d_ws);
    hipLaunchKernelGGL(maha_kernel, dim3(8 * CPX * 16), dim3(256), 0, stream, z, d_ws);
    hipLaunchKernelGGL(finalize_kernel, dim3((NPAD + 255) / 256), dim3(256), 0, stream, d_ws, out);
}